// Round 5
// baseline (310.116 us; speedup 1.0000x reference)
//
#include <hip/hip_runtime.h>
#include <hip/hip_fp16.h>
#include <hip/hip_cooperative_groups.h>
#include <math.h>

namespace cg = cooperative_groups;

#define N_NODES 10000
#define N_EDGES 160000
#define TBL_N 512               // intervals; TBL_N+1 rows (lerp err ~3e-4 + fp16 ~5e-4 << 1.3 thr)
#define ACT_C 1.676518f         // 1/sqrt(E[silu(z)^2]), z~N(0,1)
#define CAP 64                  // bucket capacity per node (mean valid degree ~15.4; P(>64)~e^-40)
#define S3 1.7320508075688772f
#define GRID 1024               // 4 blocks/CU x 256 CU -> co-resident for cooperative launch
#define TBL_BLOCKS 129          // 516 waves >= 513 table rows

// mix table, fp16-packed: lane u holds {half2(mA,mB), half2(mC,mD)} for channels {u,64+u,128+u,192+u}
__device__ uint2  g_tbl[(TBL_N + 1) * 64];
// per-node fp16 features: [0,64): m0 | [64,192): (vx,vy) half2 per channel | [192,256): vz
__device__ __half g_nd[N_NODES * 256];
__device__ int    g_cnt[N_NODES];
// bucket record: {yhat_x, yhat_y, yhat_z, bits = sender<<18 | idx<<9 | frac9}
__device__ float4 g_bkt[N_NODES * CAP];

__device__ __forceinline__ void edge_body(int j, const float4& myrec,
                                          int u, float& accA, float& accB,
                                          float& aCx, float& aCy, float& aCz,
                                          float& aDx, float& aDy, float& aDz) {
    float yx = __shfl(myrec.x, j);
    float yy = __shfl(myrec.y, j);
    float yz = __shfl(myrec.z, j);
    unsigned int bits = __float_as_uint(__shfl(myrec.w, j));
    int sv = (int)(bits >> 18);
    int i  = (int)((bits >> 9) & 511u);
    float f = (float)(bits & 511u) * (1.0f / 512.0f);

    uint2 q0 = g_tbl[i * 64 + u];           // coalesced 512B/wave, L2-resident (262KB table)
    uint2 q1 = g_tbl[i * 64 + 64 + u];
    const __half* nd = g_nd + sv * 256;
    float m0u = __half2float(nd[u]);
    float2 vxy = __half22float2(*(const __half2*)(nd + 64 + 2 * u));
    float vz_ = __half2float(nd[192 + u]);

    float2 a0 = __half22float2(*(__half2*)&q0.x);   // (mA, mB) at row i
    float2 b0 = __half22float2(*(__half2*)&q0.y);   // (mC, mD)
    float2 a1 = __half22float2(*(__half2*)&q1.x);
    float2 b1 = __half22float2(*(__half2*)&q1.y);
    float mA = fmaf(f, a1.x - a0.x, a0.x);
    float mB = fmaf(f, a1.y - a0.y, a0.y);
    float mC = fmaf(f, b1.x - b0.x, b0.x);
    float mD = fmaf(f, b1.y - b0.y, b0.y);

    float tp0 = fmaf(vxy.x, yx, fmaf(vxy.y, yy, vz_ * yz));
    accA = fmaf(m0u, mA, accA);
    accB = fmaf(tp0, mB, accB);
    aCx = fmaf(mC, vxy.x, aCx);
    aCy = fmaf(mC, vxy.y, aCy);
    aCz = fmaf(mC, vz_,   aCz);
    float cD = m0u * mD * S3;
    aDx = fmaf(cD, yx, aDx);
    aDy = fmaf(cD, yy, aDy);
    aDz = fmaf(cD, yz, aDz);
}

__global__ __launch_bounds__(256, 4) void fused_kernel(
    const float* __restrict__ W1, const float* __restrict__ W2, const float* __restrict__ W3,
    const float* __restrict__ node_scalars, const float* __restrict__ node_vectors,
    const float* __restrict__ vectors, const int* __restrict__ senders,
    const int* __restrict__ receivers, float* __restrict__ out)
{
    cg::grid_group grid = cg::this_grid();
    __shared__ float smem[2][8][64];       // phase1: table h-rows (first 1KB); phase3: combine buffer
    const int tid = threadIdx.x;
    const int lane = tid & 63;
    const int wl = tid >> 6;
    const int bx = (int)blockIdx.x;

    // ================= phase 1: table MLP | fp16 node convert | counter zero =================
    if (bx < TBL_BLOCKS) {
        int wid = bx * 4 + wl;
        if (wid > TBL_N) wid = TBL_N;      // duplicate row 512 (barrier-safe)
        const float x = (float)wid * (1.0f / (float)TBL_N);
        float x2 = x * x, x3 = x2 * x, x6 = x3 * x3;
        float env = (x < 1.0f) ? (1.0f - 28.0f * x6 + 48.0f * x6 * x - 21.0f * x6 * x2) : 0.0f;
        const float pi = 3.14159265358979f;
        float radial[8];
        #pragma unroll
        for (int k = 1; k <= 8; ++k) {
            float b = (x == 0.0f) ? ((float)k * pi) : (sinf(pi * (float)k * x) / x);
            radial[k - 1] = 1.41421356237f * b * env;
        }
        float acc = 0.0f;
        #pragma unroll
        for (int k = 0; k < 8; ++k) acc += radial[k] * W1[k * 64 + lane];
        acc *= 0.35355339059f;             // 1/sqrt(8)
        float a = ACT_C * acc / (1.0f + expf(-acc));
        smem[0][wl][lane] = a;             // wl in [0,4): rows 0..3 of smem[0]
        __syncthreads();
        acc = 0.0f;
        #pragma unroll 8
        for (int k = 0; k < 64; ++k) acc += smem[0][wl][k] * W2[k * 64 + lane];
        acc *= 0.125f;                     // 1/sqrt(64)
        a = ACT_C * acc / (1.0f + expf(-acc));
        __syncthreads();
        smem[0][wl][lane] = a;
        __syncthreads();
        float m0 = 0.f, m1 = 0.f, m2 = 0.f, m3 = 0.f;
        #pragma unroll 4
        for (int k = 0; k < 64; ++k) {
            float hk = smem[0][wl][k];
            const float* w = W3 + k * 256 + lane;
            m0 += hk * w[0];
            m1 += hk * w[64];
            m2 += hk * w[128];
            m3 += hk * w[192];
        }
        __half2 h01 = __floats2half2_rn(m0 * 0.125f, m1 * 0.125f);
        __half2 h23 = __floats2half2_rn(m2 * 0.125f, m3 * 0.125f);
        uint2 r;
        r.x = *(unsigned int*)&h01;
        r.y = *(unsigned int*)&h23;
        g_tbl[wid * 64 + lane] = r;
    } else {
        int rb = bx - TBL_BLOCKS;                          // [0, 895)
        if (rb < 40) {                                     // zero bucket counters
            int i = rb * 256 + tid;
            if (i < N_NODES) g_cnt[i] = 0;
        }
        // fp16 node-feature convert, wave-per-node grid-stride
        const int nwaves = (GRID - TBL_BLOCKS) * 4;        // 3580
        for (int n = rb * 4 + wl; n < N_NODES; n += nwaves) {
            float m0 = node_scalars[n * 64 + lane];
            const float* p = node_vectors + n * 192 + 3 * lane;
            __half* nd = g_nd + n * 256;
            nd[lane] = __float2half(m0);
            *(__half2*)(nd + 64 + 2 * lane) = __floats2half2_rn(p[0], p[1]);
            nd[192 + lane] = __float2half(p[2]);
        }
    }
    grid.sync();

    // ================= phase 2: scatter edges into receiver buckets =================
    {
        int e = bx * 256 + tid;                            // 262144 threads >= 160000 edges
        if (e < N_EDGES) {
            float vx = vectors[3 * e], vy = vectors[3 * e + 1], vz = vectors[3 * e + 2];
            float x2 = vx * vx + vy * vy + vz * vz;
            if (x2 < 1.0f) {                               // envelope==0 edges dropped
                float invx = rsqrtf(x2);
                float x = x2 * invx;
                float t = x * (float)TBL_N;
                int idx = (int)t;            if (idx > TBL_N - 1) idx = TBL_N - 1;
                int fr  = (int)((t - (float)idx) * 512.0f);  if (fr > 511) fr = 511;
                unsigned int bits = ((unsigned int)senders[e] << 18) |
                                    ((unsigned int)idx << 9) | (unsigned int)fr;
                int r = receivers[e];
                int slot = atomicAdd(&g_cnt[r], 1);
                if (slot < CAP) {                          // overflow clamp (never taken)
                    g_bkt[(r << 6) + slot] =
                        make_float4(vx * invx, vy * invx, vz * invx, __uint_as_float(bits));
                }
            }
        }
    }
    grid.sync();

    // ================= phase 3: gather, 2 waves per node, LDS combine =================
    const int slot = wl >> 1;          // node slot within block: 0..1
    const int half = wl & 1;           // which half of the edge list
    const int u = lane;
    for (int sweep = 0; sweep < (N_NODES + GRID * 2 - 1) / (GRID * 2); ++sweep) {
        int n = sweep * (GRID * 2) + bx * 2 + slot;
        bool active = (n < N_NODES);
        float accA = 0.f, accB = 0.f;
        float aCx = 0.f, aCy = 0.f, aCz = 0.f;
        float aDx = 0.f, aDy = 0.f, aDz = 0.f;
        if (active) {
            const int base = n << 6;
            int cnt = g_cnt[n]; if (cnt > CAP) cnt = CAP;
            int cnt2 = (cnt + 1) >> 1;
            int beg = half * cnt2;
            int len = cnt - beg; if (len > cnt2) len = cnt2; if (len < 0) len = 0;
            // hoist this half's records: lane j holds edge (beg+j); broadcast via shfl
            const float4 myrec = g_bkt[base + beg + (u < len ? u : 0)];
            int j = 0;
            for (; j + 2 <= len; j += 2) {
                edge_body(j,     myrec, u, accA, accB, aCx, aCy, aCz, aDx, aDy, aDz);
                edge_body(j + 1, myrec, u, accA, accB, aCx, aCy, aCz, aDx, aDy, aDz);
            }
            if (j < len)
                edge_body(j,     myrec, u, accA, accB, aCx, aCy, aCz, aDx, aDy, aDz);
        }
        if (half == 1 && active) {
            smem[slot][0][u] = accA;  smem[slot][1][u] = accB;
            smem[slot][2][u] = aCx;   smem[slot][3][u] = aCy;
            smem[slot][4][u] = aCz;   smem[slot][5][u] = aDx;
            smem[slot][6][u] = aDy;   smem[slot][7][u] = aDz;
        }
        __syncthreads();
        if (half == 0 && active) {
            accA += smem[slot][0][u]; accB += smem[slot][1][u];
            aCx  += smem[slot][2][u]; aCy  += smem[slot][3][u];
            aCz  += smem[slot][4][u]; aDx  += smem[slot][5][u];
            aDy  += smem[slot][6][u]; aDz  += smem[slot][7][u];
            const float inv = 0.25f;       // 1/sqrt(AVG_NEIGH)
            float* o = out + (size_t)n * 512;
            o[u]       = inv * accA;
            o[64 + u]  = inv * accB;
            o[128 + 3 * u + 0] = inv * aCx;
            o[128 + 3 * u + 1] = inv * aCy;
            o[128 + 3 * u + 2] = inv * aCz;
            o[320 + 3 * u + 0] = inv * aDx;
            o[320 + 3 * u + 1] = inv * aDy;
            o[320 + 3 * u + 2] = inv * aDz;
        }
        __syncthreads();                   // protect smem for next sweep
    }
}

extern "C" void kernel_launch(void* const* d_in, const int* in_sizes, int n_in,
                              void* d_out, int out_size, void* d_ws, size_t ws_size,
                              hipStream_t stream) {
    const float* vectors      = (const float*)d_in[0];
    const float* node_scalars = (const float*)d_in[1];
    const float* node_vectors = (const float*)d_in[2];
    const int*   senders      = (const int*)d_in[3];
    const int*   receivers    = (const int*)d_in[4];
    const float* W1           = (const float*)d_in[5];
    const float* W2           = (const float*)d_in[6];
    const float* W3           = (const float*)d_in[7];
    float* out = (float*)d_out;

    void* args[] = { (void*)&W1, (void*)&W2, (void*)&W3,
                     (void*)&node_scalars, (void*)&node_vectors,
                     (void*)&vectors, (void*)&senders, (void*)&receivers,
                     (void*)&out };
    hipLaunchCooperativeKernel((const void*)fused_kernel, dim3(GRID), dim3(256),
                               args, 0, stream);
    // out fully written per node (all 512 channels) -> no memset needed
}

// Round 6
// 43.605 us; speedup vs baseline: 7.1120x; 7.1120x over previous
//
#include <hip/hip_runtime.h>
#include <hip/hip_fp16.h>
#include <math.h>

#define N_NODES 10000
#define N_EDGES 160000
#define TBL_N 512               // intervals; rows 0..512 (lerp err ~3e-4 + fp16 ~5e-4 << 1.3 thr)
#define ACT_C 1.676518f         // 1/sqrt(E[silu(z)^2]), z~N(0,1)
#define CAP 64                  // bucket capacity per node (mean valid degree ~15.4; P(>64)~e^-40)
#define S3 1.7320508075688772f

#define SCAT_BLOCKS 625         // 160000 edges / 256
#define CONV_BLOCKS 2500        // 4 nodes per block (wave-per-node)
#define TBL_BLOCKS  129         // 516 waves >= 513 rows

// pair-row table: slot i (lane u) = {(mA,mB)@i, (mC,mD)@i, (mA,mB)@i+1, (mC,mD)@i+1} as 4x half2
__device__ uint4  g_tblp[TBL_N * 64];
// packed node features: lane u = half4 {m0, vx, vy, vz} as 2x half2
__device__ uint2  g_nd2[N_NODES * 64];
// counters: zero at module load (.bss); gather resets to zero at end of EVERY call
__device__ int    g_cnt[N_NODES];
// bucket record: {yhat_x, yhat_y, yhat_z, bits = sender<<18 | idx<<9 | frac9}
__device__ float4 g_bkt[N_NODES * CAP];

__device__ __forceinline__ float2 h2f(unsigned int v) {
    __half2 h = *(__half2*)&v;
    return __half22float2(h);
}

// Fused prep+scatter: roles by blockIdx. No inter-role dependencies:
// scatter needs only g_cnt==0 (guaranteed by previous gather / module load).
__global__ __launch_bounds__(256) void prep_scatter(
    const float* __restrict__ W1, const float* __restrict__ W2, const float* __restrict__ W3,
    const float* __restrict__ node_scalars, const float* __restrict__ node_vectors,
    const float* __restrict__ vectors, const int* __restrict__ senders,
    const int* __restrict__ receivers)
{
    const int bx = (int)blockIdx.x;
    const int tid = threadIdx.x;
    const int lane = tid & 63;
    const int wl = tid >> 6;

    if (bx < SCAT_BLOCKS) {                    // ---- scatter edges into receiver buckets ----
        int e = bx * 256 + tid;
        if (e < N_EDGES) {
            float vx = vectors[3 * e], vy = vectors[3 * e + 1], vz = vectors[3 * e + 2];
            float x2 = vx * vx + vy * vy + vz * vz;
            if (x2 < 1.0f) {                   // envelope==0 edges dropped
                float invx = rsqrtf(x2);
                float x = x2 * invx;
                float t = x * (float)TBL_N;
                int idx = (int)t;            if (idx > TBL_N - 1) idx = TBL_N - 1;
                int fr  = (int)((t - (float)idx) * 512.0f);  if (fr > 511) fr = 511;
                unsigned int bits = ((unsigned int)senders[e] << 18) |
                                    ((unsigned int)idx << 9) | (unsigned int)fr;
                int r = receivers[e];
                int slot = atomicAdd(&g_cnt[r], 1);
                if (slot < CAP)                // overflow clamp (never taken in practice)
                    g_bkt[(r << 6) + slot] =
                        make_float4(vx * invx, vy * invx, vz * invx, __uint_as_float(bits));
            }
        }
        return;
    }
    if (bx < SCAT_BLOCKS + CONV_BLOCKS) {      // ---- fp16 node-feature packing ----
        int n = (bx - SCAT_BLOCKS) * 4 + wl;   // exactly covers [0,10000)
        float m0 = node_scalars[n * 64 + lane];
        const float* p = node_vectors + n * 192 + 3 * lane;
        __half2 h01 = __floats2half2_rn(m0, p[0]);
        __half2 h23 = __floats2half2_rn(p[1], p[2]);
        uint2 r;
        r.x = *(unsigned int*)&h01;
        r.y = *(unsigned int*)&h23;
        g_nd2[n * 64 + lane] = r;
        return;
    }

    // ---- mix-table MLP (wave-per-row), pair-row packed store ----
    __shared__ float h[4][64];
    int wid = (bx - SCAT_BLOCKS - CONV_BLOCKS) * 4 + wl;
    if (wid > TBL_N) wid = TBL_N;              // duplicates write identical bytes (benign)
    const float x = (float)wid * (1.0f / (float)TBL_N);
    float x2 = x * x, x3 = x2 * x, x6 = x3 * x3;
    float env = (x < 1.0f) ? (1.0f - 28.0f * x6 + 48.0f * x6 * x - 21.0f * x6 * x2) : 0.0f;
    const float pi = 3.14159265358979f;
    float radial[8];
    #pragma unroll
    for (int k = 1; k <= 8; ++k) {
        float b = (x == 0.0f) ? ((float)k * pi) : (sinf(pi * (float)k * x) / x);
        radial[k - 1] = 1.41421356237f * b * env;
    }
    float acc = 0.0f;
    #pragma unroll
    for (int k = 0; k < 8; ++k) acc += radial[k] * W1[k * 64 + lane];
    acc *= 0.35355339059f;                     // 1/sqrt(8)
    float a = ACT_C * acc / (1.0f + expf(-acc));
    h[wl][lane] = a;
    __syncthreads();
    acc = 0.0f;
    #pragma unroll 8
    for (int k = 0; k < 64; ++k) acc += h[wl][k] * W2[k * 64 + lane];
    acc *= 0.125f;                             // 1/sqrt(64)
    a = ACT_C * acc / (1.0f + expf(-acc));
    __syncthreads();
    h[wl][lane] = a;
    __syncthreads();
    float m0 = 0.f, m1 = 0.f, m2 = 0.f, m3 = 0.f;
    #pragma unroll 4
    for (int k = 0; k < 64; ++k) {
        float hk = h[wl][k];
        const float* w = W3 + k * 256 + lane;
        m0 += hk * w[0];
        m1 += hk * w[64];
        m2 += hk * w[128];
        m3 += hk * w[192];
    }
    __half2 h01 = __floats2half2_rn(m0 * 0.125f, m1 * 0.125f);
    __half2 h23 = __floats2half2_rn(m2 * 0.125f, m3 * 0.125f);
    uint2 r;
    r.x = *(unsigned int*)&h01;
    r.y = *(unsigned int*)&h23;
    // row wid is the FIRST half of pair-slot wid, and the SECOND half of pair-slot wid-1
    if (wid < TBL_N) *(uint2*)&g_tblp[wid * 64 + lane] = r;
    if (wid >= 1)    *(uint2*)((char*)&g_tblp[(wid - 1) * 64 + lane] + 8) = r;
}

__device__ __forceinline__ void edge_body(int j, const float4& myrec,
                                          int u, float& accA, float& accB,
                                          float& aCx, float& aCy, float& aCz,
                                          float& aDx, float& aDy, float& aDz) {
    float yx = __shfl(myrec.x, j);
    float yy = __shfl(myrec.y, j);
    float yz = __shfl(myrec.z, j);
    unsigned int bits = __float_as_uint(__shfl(myrec.w, j));
    int sv = (int)(bits >> 18);
    int i  = (int)((bits >> 9) & 511u);
    float f = (float)(bits & 511u) * (1.0f / 512.0f);

    uint4 q  = g_tblp[i * 64 + u];             // ONE 16B load: both lerp rows (L2-resident 512KB)
    uint2 nv = g_nd2[sv * 64 + u];             // ONE 8B load: {m0,vx,vy,vz}

    float2 a0 = h2f(q.x);                      // (mA,mB) @ i
    float2 b0 = h2f(q.y);                      // (mC,mD) @ i
    float2 a1 = h2f(q.z);                      // (mA,mB) @ i+1
    float2 b1 = h2f(q.w);                      // (mC,mD) @ i+1
    float2 p01 = h2f(nv.x);                    // (m0, vx)
    float2 p23 = h2f(nv.y);                    // (vy, vz)

    float mA = fmaf(f, a1.x - a0.x, a0.x);
    float mB = fmaf(f, a1.y - a0.y, a0.y);
    float mC = fmaf(f, b1.x - b0.x, b0.x);
    float mD = fmaf(f, b1.y - b0.y, b0.y);

    float m0u = p01.x, vx = p01.y, vy = p23.x, vzv = p23.y;
    float tp0 = fmaf(vx, yx, fmaf(vy, yy, vzv * yz));
    accA = fmaf(m0u, mA, accA);
    accB = fmaf(tp0, mB, accB);
    aCx = fmaf(mC, vx,  aCx);
    aCy = fmaf(mC, vy,  aCy);
    aCz = fmaf(mC, vzv, aCz);
    float cD = m0u * mD * S3;
    aDx = fmaf(cD, yx, aDx);
    aDy = fmaf(cD, yy, aDy);
    aDz = fmaf(cD, yz, aDz);
}

// One block per node, 4 waves split the edge list (serial chain ~4), LDS combine.
__global__ __launch_bounds__(256) void gather_kernel(float* __restrict__ out) {
    __shared__ float smem[3][8][64];
    const int n = (int)blockIdx.x;
    const int u = threadIdx.x & 63;
    const int w = threadIdx.x >> 6;

    int cnt = g_cnt[n]; if (cnt > CAP) cnt = CAP;
    int ql = (cnt + 3) >> 2;
    int beg = w * ql;
    int len = cnt - beg; if (len > ql) len = ql; if (len < 0) len = 0;
    const int base = n << 6;
    // hoist this quarter's records: lane j holds edge (beg+j); broadcast via shfl
    const float4 myrec = g_bkt[base + beg + (u < len ? u : 0)];

    float accA = 0.f, accB = 0.f;
    float aCx = 0.f, aCy = 0.f, aCz = 0.f;
    float aDx = 0.f, aDy = 0.f, aDz = 0.f;
    int j = 0;
    for (; j + 2 <= len; j += 2) {
        edge_body(j,     myrec, u, accA, accB, aCx, aCy, aCz, aDx, aDy, aDz);
        edge_body(j + 1, myrec, u, accA, accB, aCx, aCy, aCz, aDx, aDy, aDz);
    }
    if (j < len)
        edge_body(j,     myrec, u, accA, accB, aCx, aCy, aCz, aDx, aDy, aDz);

    if (w > 0) {
        smem[w - 1][0][u] = accA;  smem[w - 1][1][u] = accB;
        smem[w - 1][2][u] = aCx;   smem[w - 1][3][u] = aCy;
        smem[w - 1][4][u] = aCz;   smem[w - 1][5][u] = aDx;
        smem[w - 1][6][u] = aDy;   smem[w - 1][7][u] = aDz;
    }
    __syncthreads();
    if (w == 0) {
        #pragma unroll
        for (int s = 0; s < 3; ++s) {
            accA += smem[s][0][u]; accB += smem[s][1][u];
            aCx  += smem[s][2][u]; aCy  += smem[s][3][u];
            aCz  += smem[s][4][u]; aDx  += smem[s][5][u];
            aDy  += smem[s][6][u]; aDz  += smem[s][7][u];
        }
        const float inv = 0.25f;               // 1/sqrt(AVG_NEIGH)
        float* o = out + (size_t)n * 512;
        o[u]       = inv * accA;
        o[64 + u]  = inv * accB;
        o[128 + 3 * u + 0] = inv * aCx;
        o[128 + 3 * u + 1] = inv * aCy;
        o[128 + 3 * u + 2] = inv * aCz;
        o[320 + 3 * u + 0] = inv * aDx;
        o[320 + 3 * u + 1] = inv * aDy;
        o[320 + 3 * u + 2] = inv * aDz;
    }
    if (threadIdx.x == 0) g_cnt[n] = 0;        // after barrier: all waves have read cnt
}

extern "C" void kernel_launch(void* const* d_in, const int* in_sizes, int n_in,
                              void* d_out, int out_size, void* d_ws, size_t ws_size,
                              hipStream_t stream) {
    const float* vectors      = (const float*)d_in[0];
    const float* node_scalars = (const float*)d_in[1];
    const float* node_vectors = (const float*)d_in[2];
    const int*   senders      = (const int*)d_in[3];
    const int*   receivers    = (const int*)d_in[4];
    const float* W1           = (const float*)d_in[5];
    const float* W2           = (const float*)d_in[6];
    const float* W3           = (const float*)d_in[7];
    float* out = (float*)d_out;

    prep_scatter<<<SCAT_BLOCKS + CONV_BLOCKS + TBL_BLOCKS, 256, 0, stream>>>(
        W1, W2, W3, node_scalars, node_vectors, vectors, senders, receivers);
    gather_kernel<<<N_NODES, 256, 0, stream>>>(out);
    // out fully written per node (all 512 channels) -> no memset needed
}